// Round 1
// baseline (1922.524 us; speedup 1.0000x reference)
//
#include <hip/hip_runtime.h>

#define D      128
#define D4     32      // D / 4 (float4 slots per row)
#define ROWS   16      // rows per node-GEMM block

// ---------------------------------------------------------------------------
// Kernel 1: edge scatter.  A[d] += ego[s] * (norm[s]*norm[d])
// One 32-lane group per edge, float4 per lane (32*4 = 128 floats).
// ---------------------------------------------------------------------------
__global__ __launch_bounds__(256) void edge_scatter(
    const float* __restrict__ ego,
    const float* __restrict__ norm,
    const int*   __restrict__ src,
    const int*   __restrict__ dst,
    float*       __restrict__ A,
    int E)
{
    int t = blockIdx.x * blockDim.x + threadIdx.x;
    int e = t >> 5;
    if (e >= E) return;
    int lane = t & 31;

    int s = src[e];
    int d = dst[e];
    float c = norm[s] * norm[d];

    const float4* ego4 = (const float4*)ego;
    float4 hs = ego4[(size_t)s * D4 + lane];

    float* base = A + (size_t)d * D + lane * 4;
    atomicAdd(base + 0, hs.x * c);
    atomicAdd(base + 1, hs.y * c);
    atomicAdd(base + 2, hs.z * c);
    atomicAdd(base + 3, hs.w * c);
}

// ---------------------------------------------------------------------------
// Kernel 2: fused node update.
//   P = A + ego ; Q = ego .* A
//   h = P @ W1 + Q @ W2          (f32, vector ALU)
//   h = leaky_relu(h, 0.2) ; h /= max(||h||_2, 1e-12)
// A lives in d_out (in-place: each block reads/writes only its own rows).
// Block: 256 threads, 16 rows x 128 cols, 8 outputs per thread.
// ---------------------------------------------------------------------------
__global__ __launch_bounds__(256) void node_gemm(
    const float* __restrict__ ego,
    const float* __restrict__ W1,
    const float* __restrict__ W2,
    float*       __restrict__ Aout,   // in: aggregate A, out: h
    int N)
{
    __shared__ float P[ROWS][D];
    __shared__ float Q[ROWS][D];

    const int t    = threadIdx.x;
    const int row0 = blockIdx.x * ROWS;

    // ---- stage P, Q into LDS (2 float4 per thread per array) ----
    const float4* A4 = (const float4*)Aout;
    const float4* G4 = (const float4*)ego;
    #pragma unroll
    for (int i = 0; i < 2; ++i) {
        int idx = t + i * 256;            // 0..511 float4 slots (16 rows * 32)
        int r   = idx >> 5;
        int c4  = idx & 31;
        int row = row0 + r;
        if (row < N) {
            float4 a = A4[(size_t)row * D4 + c4];
            float4 g = G4[(size_t)row * D4 + c4];
            float4 p = {a.x + g.x, a.y + g.y, a.z + g.z, a.w + g.w};
            float4 q = {a.x * g.x, a.y * g.y, a.z * g.z, a.w * g.w};
            *(float4*)&P[r][c4 * 4] = p;
            *(float4*)&Q[r][c4 * 4] = q;
        }
    }
    __syncthreads();

    // ---- main GEMM loop: thread owns col c for 8 rows ----
    const int c  = t & 127;
    const int rh = (t >> 7) * 8;          // 0 or 8
    float acc[8] = {0.f, 0.f, 0.f, 0.f, 0.f, 0.f, 0.f, 0.f};

    for (int k = 0; k < D; k += 4) {
        float w1v[4], w2v[4];
        #pragma unroll
        for (int kk = 0; kk < 4; ++kk) {
            w1v[kk] = W1[(k + kk) * D + c];
            w2v[kk] = W2[(k + kk) * D + c];
        }
        #pragma unroll
        for (int r = 0; r < 8; ++r) {
            float4 p = *(const float4*)&P[rh + r][k];
            float4 q = *(const float4*)&Q[rh + r][k];
            float a = acc[r];
            a = fmaf(p.x, w1v[0], a);
            a = fmaf(p.y, w1v[1], a);
            a = fmaf(p.z, w1v[2], a);
            a = fmaf(p.w, w1v[3], a);
            a = fmaf(q.x, w2v[0], a);
            a = fmaf(q.y, w2v[1], a);
            a = fmaf(q.z, w2v[2], a);
            a = fmaf(q.w, w2v[3], a);
            acc[r] = a;
        }
    }

    // ---- epilogue: leaky relu, stash rows in LDS for row reduction ----
    __syncthreads();                       // done reading P/Q
    #pragma unroll
    for (int r = 0; r < 8; ++r) {
        float h = acc[r];
        h = (h >= 0.f) ? h : 0.2f * h;
        P[rh + r][c] = h;
    }
    __syncthreads();

    // ---- row-wise L2 normalize: 16 lanes per row, 8 cols per lane ----
    const int row = t >> 4;                // 0..15
    const int l   = t & 15;
    float h8[8];
    float ssum = 0.f;
    #pragma unroll
    for (int j = 0; j < 8; ++j) {
        float v = P[row][l * 8 + j];
        h8[j] = v;
        ssum += v * v;
    }
    #pragma unroll
    for (int off = 1; off < 16; off <<= 1)
        ssum += __shfl_xor(ssum, off, 16);

    float inv = 1.0f / fmaxf(sqrtf(ssum), 1e-12f);

    int orow = row0 + row;
    if (orow < N) {
        float4* O4 = (float4*)Aout;
        float4 o0 = {h8[0] * inv, h8[1] * inv, h8[2] * inv, h8[3] * inv};
        float4 o1 = {h8[4] * inv, h8[5] * inv, h8[6] * inv, h8[7] * inv};
        O4[(size_t)orow * D4 + l * 2 + 0] = o0;
        O4[(size_t)orow * D4 + l * 2 + 1] = o1;
    }
}

// ---------------------------------------------------------------------------
extern "C" void kernel_launch(void* const* d_in, const int* in_sizes, int n_in,
                              void* d_out, int out_size, void* d_ws, size_t ws_size,
                              hipStream_t stream)
{
    const float* ego  = (const float*)d_in[0];
    const float* norm = (const float*)d_in[1];
    const int*   src  = (const int*)d_in[2];
    const int*   dst  = (const int*)d_in[3];
    const float* W1   = (const float*)d_in[4];
    const float* W2   = (const float*)d_in[5];

    const int N = in_sizes[1];   // norm has N elements
    const int E = in_sizes[2];   // src has E elements

    float* out = (float*)d_out;  // used as aggregate A, then overwritten with h

    // zero the aggregate (graph-capturable, stream-ordered)
    hipMemsetAsync(out, 0, (size_t)N * D * sizeof(float), stream);

    // edge scatter: 32 threads per edge
    {
        long long total = (long long)E * 32;
        int blocks = (int)((total + 255) / 256);
        edge_scatter<<<blocks, 256, 0, stream>>>(ego, norm, src, dst, out, E);
    }

    // fused node GEMM + leaky relu + L2 normalize (in-place on out)
    {
        int blocks = (N + ROWS - 1) / ROWS;
        node_gemm<<<blocks, 256, 0, stream>>>(ego, W1, W2, out, N);
    }
}

// Round 2
// 624.783 us; speedup vs baseline: 3.0771x; 3.0771x over previous
//
#include <hip/hip_runtime.h>

#define D      128
#define D4     32      // D / 4 (float4 slots per row)
#define ROWS   16      // rows per node-GEMM block

// ---------------------------------------------------------------------------
// FALLBACK Kernel (used only if ws_size is too small): atomic edge scatter.
// ---------------------------------------------------------------------------
__global__ __launch_bounds__(256) void edge_scatter(
    const float* __restrict__ ego,
    const float* __restrict__ norm,
    const int*   __restrict__ src,
    const int*   __restrict__ dst,
    float*       __restrict__ A,
    int E)
{
    int t = blockIdx.x * blockDim.x + threadIdx.x;
    int e = t >> 5;
    if (e >= E) return;
    int lane = t & 31;

    int s = src[e];
    int d = dst[e];
    float c = norm[s] * norm[d];

    const float4* ego4 = (const float4*)ego;
    float4 hs = ego4[(size_t)s * D4 + lane];

    float* base = A + (size_t)d * D + lane * 4;
    atomicAdd(base + 0, hs.x * c);
    atomicAdd(base + 1, hs.y * c);
    atomicAdd(base + 2, hs.z * c);
    atomicAdd(base + 3, hs.w * c);
}

// ---------------------------------------------------------------------------
// Sorted path kernel 1: histogram of dst.
// ---------------------------------------------------------------------------
__global__ __launch_bounds__(256) void hist_kernel(
    const int* __restrict__ dst, int* __restrict__ cnt, int E)
{
    int e = blockIdx.x * blockDim.x + threadIdx.x;
    if (e < E) atomicAdd(&cnt[dst[e]], 1);
}

// ---------------------------------------------------------------------------
// Sorted path kernel 2: single-block exclusive scan of cnt -> off, cursor.
// cursor may alias cnt (we read cnt[i] before overwriting).
// ---------------------------------------------------------------------------
__global__ __launch_bounds__(1024) void scan_kernel(
    int* __restrict__ cnt, int* __restrict__ off, int* __restrict__ cursor, int N)
{
    __shared__ int sums[1024];
    const int t = threadIdx.x;
    const int chunk = (N + 1023) >> 10;
    const int lo = t * chunk;
    const int hi = min(N, lo + chunk);

    int s = 0;
    for (int i = lo; i < hi; ++i) s += cnt[i];
    sums[t] = s;
    __syncthreads();

    // Hillis-Steele inclusive scan over 1024 partial sums
    for (int o = 1; o < 1024; o <<= 1) {
        int v = (t >= o) ? sums[t - o] : 0;
        __syncthreads();
        sums[t] += v;
        __syncthreads();
    }
    int run = sums[t] - s;   // exclusive prefix of this thread's chunk

    for (int i = lo; i < hi; ++i) {
        int c = cnt[i];      // read BEFORE writing cursor (cursor aliases cnt)
        off[i]    = run;
        cursor[i] = run;
        run += c;
    }
}

// ---------------------------------------------------------------------------
// Sorted path kernel 3: reorder edges into CSR-by-dst, materializing
// per-edge (src index, norm[s]*norm[d]).
// ---------------------------------------------------------------------------
__global__ __launch_bounds__(256) void reorder_kernel(
    const int*   __restrict__ src,
    const int*   __restrict__ dst,
    const float* __restrict__ norm,
    int*         __restrict__ cursor,
    int*         __restrict__ srcs,
    float*       __restrict__ coef,
    int E)
{
    int e = blockIdx.x * blockDim.x + threadIdx.x;
    if (e >= E) return;
    int d = dst[e];
    int s = src[e];
    int pos = atomicAdd(&cursor[d], 1);
    srcs[pos] = s;
    coef[pos] = norm[s] * norm[d];
}

// ---------------------------------------------------------------------------
// Sorted path kernel 4: atomic-free segment reduction.
// One 32-lane group per dst node; float4 per lane (32*4 = 128 floats).
// After reorder, cursor[d] == segment end.
// ---------------------------------------------------------------------------
__global__ __launch_bounds__(256) void aggregate_kernel(
    const float* __restrict__ ego,
    const int*   __restrict__ off,
    const int*   __restrict__ cursor,
    const int*   __restrict__ srcs,
    const float* __restrict__ coef,
    float*       __restrict__ A,
    int N)
{
    int g = blockIdx.x * (blockDim.x >> 5) + (threadIdx.x >> 5);
    if (g >= N) return;
    int lane = threadIdx.x & 31;

    int i   = off[g];
    int end = cursor[g];

    const float4* ego4 = (const float4*)ego;
    float4 acc0 = {0.f, 0.f, 0.f, 0.f};
    float4 acc1 = {0.f, 0.f, 0.f, 0.f};

    for (; i + 1 < end; i += 2) {
        int   s0 = srcs[i],     s1 = srcs[i + 1];
        float c0 = coef[i],     c1 = coef[i + 1];
        float4 v0 = ego4[(size_t)s0 * D4 + lane];
        float4 v1 = ego4[(size_t)s1 * D4 + lane];
        acc0.x = fmaf(v0.x, c0, acc0.x);
        acc0.y = fmaf(v0.y, c0, acc0.y);
        acc0.z = fmaf(v0.z, c0, acc0.z);
        acc0.w = fmaf(v0.w, c0, acc0.w);
        acc1.x = fmaf(v1.x, c1, acc1.x);
        acc1.y = fmaf(v1.y, c1, acc1.y);
        acc1.z = fmaf(v1.z, c1, acc1.z);
        acc1.w = fmaf(v1.w, c1, acc1.w);
    }
    if (i < end) {
        int   s0 = srcs[i];
        float c0 = coef[i];
        float4 v0 = ego4[(size_t)s0 * D4 + lane];
        acc0.x = fmaf(v0.x, c0, acc0.x);
        acc0.y = fmaf(v0.y, c0, acc0.y);
        acc0.z = fmaf(v0.z, c0, acc0.z);
        acc0.w = fmaf(v0.w, c0, acc0.w);
    }
    acc0.x += acc1.x; acc0.y += acc1.y; acc0.z += acc1.z; acc0.w += acc1.w;

    ((float4*)A)[(size_t)g * D4 + lane] = acc0;
}

// ---------------------------------------------------------------------------
// Kernel 5: fused node update (unchanged from round 1).
//   P = A + ego ; Q = ego .* A
//   h = P @ W1 + Q @ W2 ; leaky_relu(0.2) ; row-wise L2 normalize
// A lives in d_out (in-place).
// ---------------------------------------------------------------------------
__global__ __launch_bounds__(256) void node_gemm(
    const float* __restrict__ ego,
    const float* __restrict__ W1,
    const float* __restrict__ W2,
    float*       __restrict__ Aout,
    int N)
{
    __shared__ float P[ROWS][D];
    __shared__ float Q[ROWS][D];

    const int t    = threadIdx.x;
    const int row0 = blockIdx.x * ROWS;

    const float4* A4 = (const float4*)Aout;
    const float4* G4 = (const float4*)ego;
    #pragma unroll
    for (int i = 0; i < 2; ++i) {
        int idx = t + i * 256;
        int r   = idx >> 5;
        int c4  = idx & 31;
        int row = row0 + r;
        if (row < N) {
            float4 a = A4[(size_t)row * D4 + c4];
            float4 g = G4[(size_t)row * D4 + c4];
            float4 p = {a.x + g.x, a.y + g.y, a.z + g.z, a.w + g.w};
            float4 q = {a.x * g.x, a.y * g.y, a.z * g.z, a.w * g.w};
            *(float4*)&P[r][c4 * 4] = p;
            *(float4*)&Q[r][c4 * 4] = q;
        }
    }
    __syncthreads();

    const int c  = t & 127;
    const int rh = (t >> 7) * 8;
    float acc[8] = {0.f, 0.f, 0.f, 0.f, 0.f, 0.f, 0.f, 0.f};

    for (int k = 0; k < D; k += 4) {
        float w1v[4], w2v[4];
        #pragma unroll
        for (int kk = 0; kk < 4; ++kk) {
            w1v[kk] = W1[(k + kk) * D + c];
            w2v[kk] = W2[(k + kk) * D + c];
        }
        #pragma unroll
        for (int r = 0; r < 8; ++r) {
            float4 p = *(const float4*)&P[rh + r][k];
            float4 q = *(const float4*)&Q[rh + r][k];
            float a = acc[r];
            a = fmaf(p.x, w1v[0], a);
            a = fmaf(p.y, w1v[1], a);
            a = fmaf(p.z, w1v[2], a);
            a = fmaf(p.w, w1v[3], a);
            a = fmaf(q.x, w2v[0], a);
            a = fmaf(q.y, w2v[1], a);
            a = fmaf(q.z, w2v[2], a);
            a = fmaf(q.w, w2v[3], a);
            acc[r] = a;
        }
    }

    __syncthreads();
    #pragma unroll
    for (int r = 0; r < 8; ++r) {
        float h = acc[r];
        h = (h >= 0.f) ? h : 0.2f * h;
        P[rh + r][c] = h;
    }
    __syncthreads();

    const int row = t >> 4;
    const int l   = t & 15;
    float h8[8];
    float ssum = 0.f;
    #pragma unroll
    for (int j = 0; j < 8; ++j) {
        float v = P[row][l * 8 + j];
        h8[j] = v;
        ssum += v * v;
    }
    #pragma unroll
    for (int off = 1; off < 16; off <<= 1)
        ssum += __shfl_xor(ssum, off, 16);

    float inv = 1.0f / fmaxf(sqrtf(ssum), 1e-12f);

    int orow = row0 + row;
    if (orow < N) {
        float4* O4 = (float4*)Aout;
        float4 o0 = {h8[0] * inv, h8[1] * inv, h8[2] * inv, h8[3] * inv};
        float4 o1 = {h8[4] * inv, h8[5] * inv, h8[6] * inv, h8[7] * inv};
        O4[(size_t)orow * D4 + l * 2 + 0] = o0;
        O4[(size_t)orow * D4 + l * 2 + 1] = o1;
    }
}

// ---------------------------------------------------------------------------
extern "C" void kernel_launch(void* const* d_in, const int* in_sizes, int n_in,
                              void* d_out, int out_size, void* d_ws, size_t ws_size,
                              hipStream_t stream)
{
    const float* ego  = (const float*)d_in[0];
    const float* norm = (const float*)d_in[1];
    const int*   src  = (const int*)d_in[2];
    const int*   dst  = (const int*)d_in[3];
    const float* W1   = (const float*)d_in[4];
    const float* W2   = (const float*)d_in[5];

    const int N = in_sizes[1];   // norm has N elements
    const int E = in_sizes[2];   // src has E elements

    float* out = (float*)d_out;  // aggregate A, then overwritten with h

    // Workspace layout for the sorted path
    int*   cnt  = (int*)d_ws;            // N ints (reused as cursor)
    int*   off  = cnt + N;               // N ints
    int*   srcs = off + N;               // E ints
    float* coef = (float*)(srcs + E);    // E floats
    size_t need = ((size_t)2 * N + (size_t)2 * E) * sizeof(int);

    if (ws_size >= need) {
        // ---- atomic-free sorted path ----
        hipMemsetAsync(cnt, 0, (size_t)N * sizeof(int), stream);

        int eb = (E + 255) / 256;
        hist_kernel<<<eb, 256, 0, stream>>>(dst, cnt, E);
        scan_kernel<<<1, 1024, 0, stream>>>(cnt, off, cnt, N);
        reorder_kernel<<<eb, 256, 0, stream>>>(src, dst, norm, cnt, srcs, coef, E);

        int gb = (N + 7) / 8;            // 8 groups of 32 lanes per block
        aggregate_kernel<<<gb, 256, 0, stream>>>(ego, off, cnt, srcs, coef, out, N);
    } else {
        // ---- fallback: atomic scatter ----
        hipMemsetAsync(out, 0, (size_t)N * D * sizeof(float), stream);
        long long total = (long long)E * 32;
        int blocks = (int)((total + 255) / 256);
        edge_scatter<<<blocks, 256, 0, stream>>>(ego, norm, src, dst, out, E);
    }

    // fused node GEMM + leaky relu + L2 normalize (in-place on out)
    {
        int blocks = (N + ROWS - 1) / ROWS;
        node_gemm<<<blocks, 256, 0, stream>>>(ego, W1, W2, out, N);
    }
}

// Round 4
// 421.612 us; speedup vs baseline: 4.5599x; 1.4819x over previous
//
#include <hip/hip_runtime.h>

#define D       128
#define D4      32      // D / 4 (float4 slots per row)
#define ROWS    16      // rows per node-GEMM block
#define SCAN_NB 256     // blocks in hierarchical scan
#define SCAN_BS 256     // threads per scan block

// ---------------------------------------------------------------------------
// FALLBACK Kernel (used only if ws_size is too small): atomic edge scatter.
// ---------------------------------------------------------------------------
__global__ __launch_bounds__(256) void edge_scatter(
    const float* __restrict__ ego,
    const float* __restrict__ norm,
    const int*   __restrict__ src,
    const int*   __restrict__ dst,
    float*       __restrict__ A,
    int E)
{
    int t = blockIdx.x * blockDim.x + threadIdx.x;
    int e = t >> 5;
    if (e >= E) return;
    int lane = t & 31;

    int s = src[e];
    int d = dst[e];
    float c = norm[s] * norm[d];

    const float4* ego4 = (const float4*)ego;
    float4 hs = ego4[(size_t)s * D4 + lane];

    float* base = A + (size_t)d * D + lane * 4;
    atomicAdd(base + 0, hs.x * c);
    atomicAdd(base + 1, hs.y * c);
    atomicAdd(base + 2, hs.z * c);
    atomicAdd(base + 3, hs.w * c);
}

// ---------------------------------------------------------------------------
// Kernel 1: histogram of dst.
// ---------------------------------------------------------------------------
__global__ __launch_bounds__(256) void hist_kernel(
    const int* __restrict__ dst, int* __restrict__ cnt, int E)
{
    int e = blockIdx.x * blockDim.x + threadIdx.x;
    if (e < E) atomicAdd(&cnt[dst[e]], 1);
}

// ---------------------------------------------------------------------------
// Hierarchical scan, phase 1: per-block coalesced reduce -> partial[b].
// ---------------------------------------------------------------------------
__global__ __launch_bounds__(SCAN_BS) void scan_reduce(
    const int* __restrict__ cnt, int* __restrict__ partial, int N)
{
    int b = blockIdx.x;
    int chunk = (N + SCAN_NB - 1) / SCAN_NB;
    int lo = b * chunk;
    int hi = min(N, lo + chunk);

    int s = 0;
    for (int i = lo + threadIdx.x; i < hi; i += SCAN_BS) s += cnt[i];

    __shared__ int wsum[SCAN_BS / 64];
    #pragma unroll
    for (int o = 32; o > 0; o >>= 1) s += __shfl_down(s, o, 64);
    int lane = threadIdx.x & 63, wid = threadIdx.x >> 6;
    if (lane == 0) wsum[wid] = s;
    __syncthreads();
    if (threadIdx.x == 0) {
        int tot = 0;
        #pragma unroll
        for (int w = 0; w < SCAN_BS / 64; ++w) tot += wsum[w];
        partial[b] = tot;
    }
}

// ---------------------------------------------------------------------------
// Hierarchical scan, phase 2: single small block exclusive-scans partial[256].
// ---------------------------------------------------------------------------
__global__ __launch_bounds__(SCAN_NB) void scan_partials(int* __restrict__ partial)
{
    __shared__ int wsum[SCAN_NB / 64];
    int t = threadIdx.x;
    int v = partial[t];
    int lane = t & 63, wid = t >> 6;
    int x = v;
    #pragma unroll
    for (int o = 1; o < 64; o <<= 1) {
        int u = __shfl_up(x, o, 64);
        if (lane >= o) x += u;
    }
    if (lane == 63) wsum[wid] = x;
    __syncthreads();
    int add = 0;
    for (int w = 0; w < wid; ++w) add += wsum[w];
    partial[t] = add + x - v;       // exclusive prefix
}

// ---------------------------------------------------------------------------
// Hierarchical scan, phase 3: per-block tile-wise scan + block offset.
// Writes off[] and cursor[] (cursor may alias cnt: each i is read before
// the owning thread writes it, with a barrier in between).
// ---------------------------------------------------------------------------
__global__ __launch_bounds__(SCAN_BS) void scan_apply(
    const int* __restrict__ cnt,
    const int* __restrict__ partial,
    int*       __restrict__ off,
    int*       __restrict__ cursor,
    int N)
{
    __shared__ int wsum[SCAN_BS / 64];
    __shared__ int carry;

    int b = blockIdx.x;
    int chunk = (N + SCAN_NB - 1) / SCAN_NB;
    int lo = b * chunk;
    int hi = min(N, lo + chunk);

    if (threadIdx.x == 0) carry = partial[b];
    __syncthreads();

    int lane = threadIdx.x & 63, wid = threadIdx.x >> 6;

    for (int base = lo; base < hi; base += SCAN_BS) {
        int i = base + threadIdx.x;
        int v = (i < hi) ? cnt[i] : 0;

        int x = v;
        #pragma unroll
        for (int o = 1; o < 64; o <<= 1) {
            int u = __shfl_up(x, o, 64);
            if (lane >= o) x += u;
        }
        if (lane == 63) wsum[wid] = x;
        __syncthreads();

        int add = carry;
        for (int w = 0; w < wid; ++w) add += wsum[w];
        int excl = add + x - v;

        if (i < hi) { off[i] = excl; cursor[i] = excl; }
        __syncthreads();
        if (threadIdx.x == SCAN_BS - 1) carry = add + x;   // carry + tile total
        __syncthreads();
    }
}

// ---------------------------------------------------------------------------
// Kernel 3: reorder edges into CSR-by-dst, materializing (src, norm product).
// ---------------------------------------------------------------------------
__global__ __launch_bounds__(256) void reorder_kernel(
    const int*   __restrict__ src,
    const int*   __restrict__ dst,
    const float* __restrict__ norm,
    int*         __restrict__ cursor,
    int*         __restrict__ srcs,
    float*       __restrict__ coef,
    int E)
{
    int e = blockIdx.x * blockDim.x + threadIdx.x;
    if (e >= E) return;
    int d = dst[e];
    int s = src[e];
    int pos = atomicAdd(&cursor[d], 1);
    srcs[pos] = s;
    coef[pos] = norm[s] * norm[d];
}

// ---------------------------------------------------------------------------
// Kernel 4: atomic-free segment reduction.
// One 32-lane group per dst node; float4 per lane (32*4 = 128 floats).
// After reorder, cursor[d] == segment end.
// ---------------------------------------------------------------------------
__global__ __launch_bounds__(256) void aggregate_kernel(
    const float* __restrict__ ego,
    const int*   __restrict__ off,
    const int*   __restrict__ cursor,
    const int*   __restrict__ srcs,
    const float* __restrict__ coef,
    float*       __restrict__ A,
    int N)
{
    int g = blockIdx.x * (blockDim.x >> 5) + (threadIdx.x >> 5);
    if (g >= N) return;
    int lane = threadIdx.x & 31;

    int i   = off[g];
    int end = cursor[g];

    const float4* ego4 = (const float4*)ego;
    float4 acc0 = {0.f, 0.f, 0.f, 0.f};
    float4 acc1 = {0.f, 0.f, 0.f, 0.f};

    for (; i + 1 < end; i += 2) {
        int   s0 = srcs[i],     s1 = srcs[i + 1];
        float c0 = coef[i],     c1 = coef[i + 1];
        float4 v0 = ego4[(size_t)s0 * D4 + lane];
        float4 v1 = ego4[(size_t)s1 * D4 + lane];
        acc0.x = fmaf(v0.x, c0, acc0.x);
        acc0.y = fmaf(v0.y, c0, acc0.y);
        acc0.z = fmaf(v0.z, c0, acc0.z);
        acc0.w = fmaf(v0.w, c0, acc0.w);
        acc1.x = fmaf(v1.x, c1, acc1.x);
        acc1.y = fmaf(v1.y, c1, acc1.y);
        acc1.z = fmaf(v1.z, c1, acc1.z);
        acc1.w = fmaf(v1.w, c1, acc1.w);
    }
    if (i < end) {
        int   s0 = srcs[i];
        float c0 = coef[i];
        float4 v0 = ego4[(size_t)s0 * D4 + lane];
        acc0.x = fmaf(v0.x, c0, acc0.x);
        acc0.y = fmaf(v0.y, c0, acc0.y);
        acc0.z = fmaf(v0.z, c0, acc0.z);
        acc0.w = fmaf(v0.w, c0, acc0.w);
    }
    acc0.x += acc1.x; acc0.y += acc1.y; acc0.z += acc1.z; acc0.w += acc1.w;

    ((float4*)A)[(size_t)g * D4 + lane] = acc0;
}

// ---------------------------------------------------------------------------
// Kernel 5: fused node update.
//   P = A + ego ; Q = ego .* A
//   h = P @ W1 + Q @ W2 ; leaky_relu(0.2) ; row-wise L2 normalize
// A lives in d_out (in-place).
// ---------------------------------------------------------------------------
__global__ __launch_bounds__(256) void node_gemm(
    const float* __restrict__ ego,
    const float* __restrict__ W1,
    const float* __restrict__ W2,
    float*       __restrict__ Aout,
    int N)
{
    __shared__ float P[ROWS][D];
    __shared__ float Q[ROWS][D];

    const int t    = threadIdx.x;
    const int row0 = blockIdx.x * ROWS;

    const float4* A4 = (const float4*)Aout;
    const float4* G4 = (const float4*)ego;
    #pragma unroll
    for (int i = 0; i < 2; ++i) {
        int idx = t + i * 256;
        int r   = idx >> 5;
        int c4  = idx & 31;
        int row = row0 + r;
        if (row < N) {
            float4 a = A4[(size_t)row * D4 + c4];
            float4 g = G4[(size_t)row * D4 + c4];
            float4 p = {a.x + g.x, a.y + g.y, a.z + g.z, a.w + g.w};
            float4 q = {a.x * g.x, a.y * g.y, a.z * g.z, a.w * g.w};
            *(float4*)&P[r][c4 * 4] = p;
            *(float4*)&Q[r][c4 * 4] = q;
        }
    }
    __syncthreads();

    const int c  = t & 127;
    const int rh = (t >> 7) * 8;
    float acc[8] = {0.f, 0.f, 0.f, 0.f, 0.f, 0.f, 0.f, 0.f};

    for (int k = 0; k < D; k += 4) {
        float w1v[4], w2v[4];
        #pragma unroll
        for (int kk = 0; kk < 4; ++kk) {
            w1v[kk] = W1[(k + kk) * D + c];
            w2v[kk] = W2[(k + kk) * D + c];
        }
        #pragma unroll
        for (int r = 0; r < 8; ++r) {
            float4 p = *(const float4*)&P[rh + r][k];
            float4 q = *(const float4*)&Q[rh + r][k];
            float a = acc[r];
            a = fmaf(p.x, w1v[0], a);
            a = fmaf(p.y, w1v[1], a);
            a = fmaf(p.z, w1v[2], a);
            a = fmaf(p.w, w1v[3], a);
            a = fmaf(q.x, w2v[0], a);
            a = fmaf(q.y, w2v[1], a);
            a = fmaf(q.z, w2v[2], a);
            a = fmaf(q.w, w2v[3], a);
            acc[r] = a;
        }
    }

    __syncthreads();
    #pragma unroll
    for (int r = 0; r < 8; ++r) {
        float h = acc[r];
        h = (h >= 0.f) ? h : 0.2f * h;
        P[rh + r][c] = h;
    }
    __syncthreads();

    const int row = t >> 4;
    const int l   = t & 15;
    float h8[8];
    float ssum = 0.f;
    #pragma unroll
    for (int j = 0; j < 8; ++j) {
        float v = P[row][l * 8 + j];
        h8[j] = v;
        ssum += v * v;
    }
    #pragma unroll
    for (int o = 1; o < 16; o <<= 1)
        ssum += __shfl_xor(ssum, o, 16);

    float inv = 1.0f / fmaxf(sqrtf(ssum), 1e-12f);

    int orow = row0 + row;
    if (orow < N) {
        float4* O4 = (float4*)Aout;
        float4 o0 = {h8[0] * inv, h8[1] * inv, h8[2] * inv, h8[3] * inv};
        float4 o1 = {h8[4] * inv, h8[5] * inv, h8[6] * inv, h8[7] * inv};
        O4[(size_t)orow * D4 + l * 2 + 0] = o0;
        O4[(size_t)orow * D4 + l * 2 + 1] = o1;
    }
}

// ---------------------------------------------------------------------------
extern "C" void kernel_launch(void* const* d_in, const int* in_sizes, int n_in,
                              void* d_out, int out_size, void* d_ws, size_t ws_size,
                              hipStream_t stream)
{
    const float* ego  = (const float*)d_in[0];
    const float* norm = (const float*)d_in[1];
    const int*   src  = (const int*)d_in[2];
    const int*   dst  = (const int*)d_in[3];
    const float* W1   = (const float*)d_in[4];
    const float* W2   = (const float*)d_in[5];

    const int N = in_sizes[1];   // norm has N elements
    const int E = in_sizes[2];   // src has E elements

    float* out = (float*)d_out;  // aggregate A, then overwritten with h

    // Workspace layout for the sorted path
    int*   cnt     = (int*)d_ws;              // N ints (reused as cursor)
    int*   off     = cnt + N;                 // N ints
    int*   srcs    = off + N;                 // E ints
    float* coef    = (float*)(srcs + E);      // E floats
    int*   partial = (int*)(coef + E);        // SCAN_NB ints
    size_t need = ((size_t)2 * N + (size_t)2 * E + SCAN_NB) * sizeof(int);

    if (ws_size >= need) {
        // ---- atomic-free sorted path ----
        hipMemsetAsync(cnt, 0, (size_t)N * sizeof(int), stream);

        int eb = (E + 255) / 256;
        hist_kernel<<<eb, 256, 0, stream>>>(dst, cnt, E);

        scan_reduce  <<<SCAN_NB, SCAN_BS, 0, stream>>>(cnt, partial, N);
        scan_partials<<<1,       SCAN_NB, 0, stream>>>(partial);
        scan_apply   <<<SCAN_NB, SCAN_BS, 0, stream>>>(cnt, partial, off, cnt, N);

        reorder_kernel<<<eb, 256, 0, stream>>>(src, dst, norm, cnt, srcs, coef, E);

        int gb = (N + 7) / 8;            // 8 groups of 32 lanes per block
        aggregate_kernel<<<gb, 256, 0, stream>>>(ego, off, cnt, srcs, coef, out, N);
    } else {
        // ---- fallback: atomic scatter ----
        hipMemsetAsync(out, 0, (size_t)N * D * sizeof(float), stream);
        long long total = (long long)E * 32;
        int blocks = (int)((total + 255) / 256);
        edge_scatter<<<blocks, 256, 0, stream>>>(ego, norm, src, dst, out, E);
    }

    // fused node GEMM + leaky relu + L2 normalize (in-place on out)
    {
        int blocks = (N + ROWS - 1) / ROWS;
        node_gemm<<<blocks, 256, 0, stream>>>(ego, W1, W2, out, N);
    }
}

// Round 7
// 321.334 us; speedup vs baseline: 5.9829x; 1.3121x over previous
//
#include <hip/hip_runtime.h>

#define D       128
#define D4      32      // D / 4 (float4 slots per row)
#define ROWS    16      // rows per fallback node-GEMM block
#define SCAN_NB 256     // blocks in hierarchical scan
#define SCAN_BS 256     // threads per scan block
#define BM      64      // rows per MFMA node-GEMM block

typedef short bf16x4 __attribute__((ext_vector_type(4)));
typedef short bf16x8 __attribute__((ext_vector_type(8)));
typedef float f32x4  __attribute__((ext_vector_type(4)));

__device__ __forceinline__ short f2bf(float x) {
    unsigned u = __builtin_bit_cast(unsigned, x);
    unsigned r = (u + 0x7FFFu + ((u >> 16) & 1u)) >> 16;
    return (short)r;
}
__device__ __forceinline__ float bf2f(short h) {
    unsigned u = ((unsigned)(unsigned short)h) << 16;
    return __builtin_bit_cast(float, u);
}

// ---------------------------------------------------------------------------
// FALLBACK: atomic edge scatter (only if ws too small).
// ---------------------------------------------------------------------------
__global__ __launch_bounds__(256) void edge_scatter(
    const float* __restrict__ ego,
    const float* __restrict__ norm,
    const int*   __restrict__ src,
    const int*   __restrict__ dst,
    float*       __restrict__ A,
    int E)
{
    int t = blockIdx.x * blockDim.x + threadIdx.x;
    int e = t >> 5;
    if (e >= E) return;
    int lane = t & 31;
    int s = src[e];
    int d = dst[e];
    float c = norm[s] * norm[d];
    const float4* ego4 = (const float4*)ego;
    float4 hs = ego4[(size_t)s * D4 + lane];
    float* base = A + (size_t)d * D + lane * 4;
    atomicAdd(base + 0, hs.x * c);
    atomicAdd(base + 1, hs.y * c);
    atomicAdd(base + 2, hs.z * c);
    atomicAdd(base + 3, hs.w * c);
}

// ---------------------------------------------------------------------------
// Kernel 1: histogram of dst.
// ---------------------------------------------------------------------------
__global__ __launch_bounds__(256) void hist_kernel(
    const int* __restrict__ dst, int* __restrict__ cnt, int E)
{
    int e = blockIdx.x * blockDim.x + threadIdx.x;
    if (e < E) atomicAdd(&cnt[dst[e]], 1);
}

// ---------------------------------------------------------------------------
// Hierarchical scan (3 phases).
// ---------------------------------------------------------------------------
__global__ __launch_bounds__(SCAN_BS) void scan_reduce(
    const int* __restrict__ cnt, int* __restrict__ partial, int N)
{
    int b = blockIdx.x;
    int chunk = (N + SCAN_NB - 1) / SCAN_NB;
    int lo = b * chunk;
    int hi = min(N, lo + chunk);

    int s = 0;
    for (int i = lo + threadIdx.x; i < hi; i += SCAN_BS) s += cnt[i];

    __shared__ int wsum[SCAN_BS / 64];
    #pragma unroll
    for (int o = 32; o > 0; o >>= 1) s += __shfl_down(s, o, 64);
    int lane = threadIdx.x & 63, wid = threadIdx.x >> 6;
    if (lane == 0) wsum[wid] = s;
    __syncthreads();
    if (threadIdx.x == 0) {
        int tot = 0;
        #pragma unroll
        for (int w = 0; w < SCAN_BS / 64; ++w) tot += wsum[w];
        partial[b] = tot;
    }
}

__global__ __launch_bounds__(SCAN_NB) void scan_partials(int* __restrict__ partial)
{
    __shared__ int wsum[SCAN_NB / 64];
    int t = threadIdx.x;
    int v = partial[t];
    int lane = t & 63, wid = t >> 6;
    int x = v;
    #pragma unroll
    for (int o = 1; o < 64; o <<= 1) {
        int u = __shfl_up(x, o, 64);
        if (lane >= o) x += u;
    }
    if (lane == 63) wsum[wid] = x;
    __syncthreads();
    int add = 0;
    for (int w = 0; w < wid; ++w) add += wsum[w];
    partial[t] = add + x - v;
}

__global__ __launch_bounds__(SCAN_BS) void scan_apply(
    const int* __restrict__ cnt,
    const int* __restrict__ partial,
    int*       __restrict__ off,
    int*       __restrict__ cursor,
    int N)
{
    __shared__ int wsum[SCAN_BS / 64];
    __shared__ int carry;

    int b = blockIdx.x;
    int chunk = (N + SCAN_NB - 1) / SCAN_NB;
    int lo = b * chunk;
    int hi = min(N, lo + chunk);

    if (threadIdx.x == 0) carry = partial[b];
    __syncthreads();

    int lane = threadIdx.x & 63, wid = threadIdx.x >> 6;

    for (int base = lo; base < hi; base += SCAN_BS) {
        int i = base + threadIdx.x;
        int v = (i < hi) ? cnt[i] : 0;

        int x = v;
        #pragma unroll
        for (int o = 1; o < 64; o <<= 1) {
            int u = __shfl_up(x, o, 64);
            if (lane >= o) x += u;
        }
        if (lane == 63) wsum[wid] = x;
        __syncthreads();

        int add = carry;
        for (int w = 0; w < wid; ++w) add += wsum[w];
        int excl = add + x - v;

        if (i < hi) { off[i] = excl; cursor[i] = excl; }
        __syncthreads();
        if (threadIdx.x == SCAN_BS - 1) carry = add + x;
        __syncthreads();
    }
}

// ---------------------------------------------------------------------------
// Kernel 3: reorder edges into CSR-by-dst.
// ---------------------------------------------------------------------------
__global__ __launch_bounds__(256) void reorder_kernel(
    const int*   __restrict__ src,
    const int*   __restrict__ dst,
    const float* __restrict__ norm,
    int*         __restrict__ cursor,
    int*         __restrict__ srcs,
    float*       __restrict__ coef,
    int E)
{
    int e = blockIdx.x * blockDim.x + threadIdx.x;
    if (e >= E) return;
    int d = dst[e];
    int s = src[e];
    int pos = atomicAdd(&cursor[d], 1);
    srcs[pos] = s;
    coef[pos] = norm[s] * norm[d];
}

// ---------------------------------------------------------------------------
// Kernel 4: atomic-free segment reduction (32 lanes / node).
// ---------------------------------------------------------------------------
__global__ __launch_bounds__(256) void aggregate_kernel(
    const float* __restrict__ ego,
    const int*   __restrict__ off,
    const int*   __restrict__ cursor,
    const int*   __restrict__ srcs,
    const float* __restrict__ coef,
    float*       __restrict__ A,
    int N)
{
    int g = blockIdx.x * (blockDim.x >> 5) + (threadIdx.x >> 5);
    if (g >= N) return;
    int lane = threadIdx.x & 31;

    int i   = off[g];
    int end = cursor[g];

    const float4* ego4 = (const float4*)ego;
    float4 acc0 = {0.f, 0.f, 0.f, 0.f};
    float4 acc1 = {0.f, 0.f, 0.f, 0.f};

    for (; i + 1 < end; i += 2) {
        int   s0 = srcs[i],     s1 = srcs[i + 1];
        float c0 = coef[i],     c1 = coef[i + 1];
        float4 v0 = ego4[(size_t)s0 * D4 + lane];
        float4 v1 = ego4[(size_t)s1 * D4 + lane];
        acc0.x = fmaf(v0.x, c0, acc0.x);
        acc0.y = fmaf(v0.y, c0, acc0.y);
        acc0.z = fmaf(v0.z, c0, acc0.z);
        acc0.w = fmaf(v0.w, c0, acc0.w);
        acc1.x = fmaf(v1.x, c1, acc1.x);
        acc1.y = fmaf(v1.y, c1, acc1.y);
        acc1.z = fmaf(v1.z, c1, acc1.z);
        acc1.w = fmaf(v1.w, c1, acc1.w);
    }
    if (i < end) {
        int   s0 = srcs[i];
        float c0 = coef[i];
        float4 v0 = ego4[(size_t)s0 * D4 + lane];
        acc0.x = fmaf(v0.x, c0, acc0.x);
        acc0.y = fmaf(v0.y, c0, acc0.y);
        acc0.z = fmaf(v0.z, c0, acc0.z);
        acc0.w = fmaf(v0.w, c0, acc0.w);
    }
    acc0.x += acc1.x; acc0.y += acc1.y; acc0.z += acc1.z; acc0.w += acc1.w;

    ((float4*)A)[(size_t)g * D4 + lane] = acc0;
}

// ---------------------------------------------------------------------------
// Kernel 4.5: precompute W fragment tables (hi/lo bf16 split), fragment-major.
// Frag f = s*8 + tn (s: k-step of 32, tn: n-tile of 16). Lane l supplies
// B[k][n] with k = s*32 + (l>>4)*8 + i, n = tn*16 + (l&15), i = 0..7.
// Wcat[k][n] = k<128 ? W1[k][n] : W2[k-128][n].
// ---------------------------------------------------------------------------
__global__ __launch_bounds__(256) void prep_w(
    const float* __restrict__ W1,
    const float* __restrict__ W2,
    short*       __restrict__ whi,
    short*       __restrict__ wlo)
{
    int pair = blockIdx.x * blockDim.x + threadIdx.x;   // (f, lane): 0..4095
    if (pair >= 4096) return;
    int l  = pair & 63;
    int f  = pair >> 6;
    int tn = f & 7;
    int s  = f >> 3;

    short h8[8], l8[8];
    #pragma unroll
    for (int i = 0; i < 8; ++i) {
        int k = s * 32 + ((l >> 4) * 8) + i;
        int n = tn * 16 + (l & 15);
        float w = (k < 128) ? W1[k * 128 + n] : W2[(k - 128) * 128 + n];
        short hi = f2bf(w);
        float rem = w - bf2f(hi);
        h8[i] = hi;
        l8[i] = f2bf(rem);
    }
    bf16x8 hv, lv;
    #pragma unroll
    for (int i = 0; i < 8; ++i) { hv[i] = h8[i]; lv[i] = l8[i]; }
    *(bf16x8*)&whi[pair * 8] = hv;
    *(bf16x8*)&wlo[pair * 8] = lv;
}

// ---------------------------------------------------------------------------
// Kernel 5: MFMA node update (split-bf16, 3-term).
//   P = A + ego ; Q = ego .* A   (staged hi/lo bf16 in LDS)
//   h = [P|Q] @ [W1;W2]  via mfma_f32_16x16x32_bf16
//   h = leaky_relu(0.2) ; row-wise L2 normalize. In-place on Aout rows.
// Block: 256 threads (4 waves), BM=64 rows. Wave w computes all 4 M-tiles
// for its 2 N-tiles (cols 32w .. 32w+31). Bh held in regs for full K.
// ---------------------------------------------------------------------------
__global__ __launch_bounds__(256) void node_gemm_mfma(
    const float* __restrict__ ego,
    const short* __restrict__ whi,
    const short* __restrict__ wlo,
    float*       __restrict__ Aout,
    int N)
{
    // [phase(P/Q)][row][k_local], padded to 136 to spread banks
    __shared__ short lds_hi[2][BM][136];
    __shared__ short lds_lo[2][BM][136];
    __shared__ float nspart[4][BM];
    __shared__ float ninv[BM];

    const int t    = threadIdx.x;
    const int lane = t & 63;
    const int w    = t >> 6;
    const int row0 = blockIdx.x * BM;

    // ---- stage P,Q as hi/lo bf16 into LDS ----
    const float4* A4 = (const float4*)Aout;
    const float4* G4 = (const float4*)ego;
    #pragma unroll
    for (int i = 0; i < 8; ++i) {
        int slot = t + i * 256;          // 0..2047 = 64 rows * 32 float4
        int r    = slot >> 5;
        int c4   = slot & 31;
        int row  = row0 + r;
        float4 a = {0.f, 0.f, 0.f, 0.f}, g = {0.f, 0.f, 0.f, 0.f};
        if (row < N) {
            a = A4[(size_t)row * D4 + c4];
            g = G4[(size_t)row * D4 + c4];
        }
        float p[4] = {a.x + g.x, a.y + g.y, a.z + g.z, a.w + g.w};
        float q[4] = {a.x * g.x, a.y * g.y, a.z * g.z, a.w * g.w};
        bf16x4 ph, pl, qh, ql;
        #pragma unroll
        for (int j = 0; j < 4; ++j) {
            short hb = f2bf(p[j]);
            ph[j] = hb;  pl[j] = f2bf(p[j] - bf2f(hb));
            short hq = f2bf(q[j]);
            qh[j] = hq;  ql[j] = f2bf(q[j] - bf2f(hq));
        }
        int kc = c4 * 4;
        *(bf16x4*)&lds_hi[0][r][kc] = ph;
        *(bf16x4*)&lds_lo[0][r][kc] = pl;
        *(bf16x4*)&lds_hi[1][r][kc] = qh;
        *(bf16x4*)&lds_lo[1][r][kc] = ql;
    }

    // ---- load Bh fragments for full K into registers ----
    const bf16x8* WH = (const bf16x8*)whi;
    const bf16x8* WL = (const bf16x8*)wlo;
    bf16x8 bh[8][2];
    #pragma unroll
    for (int s = 0; s < 8; ++s) {
        #pragma unroll
        for (int j = 0; j < 2; ++j)
            bh[s][j] = WH[(size_t)(s * 8 + 2 * w + j) * 64 + lane];
    }

    f32x4 acc[4][2];
    #pragma unroll
    for (int m = 0; m < 4; ++m)
        #pragma unroll
        for (int j = 0; j < 2; ++j)
            acc[m][j] = (f32x4){0.f, 0.f, 0.f, 0.f};

    __syncthreads();

    // ---- MFMA main loop: 8 k-steps of 32 (P: s<4, Q: s>=4) ----
    #pragma unroll
    for (int s = 0; s < 8; ++s) {
        const int ph = s >> 2;
        const int kl = (s & 3) * 32 + (lane >> 4) * 8;
        bf16x8 ah[4], al[4];
        #pragma unroll
        for (int m = 0; m < 4; ++m) {
            ah[m] = *(const bf16x8*)&lds_hi[ph][m * 16 + (lane & 15)][kl];
            al[m] = *(const bf16x8*)&lds_lo[ph][m * 16 + (lane & 15)][kl];
        }
        bf16x8 bl0 = WL[(size_t)(s * 8 + 2 * w + 0) * 64 + lane];
        bf16x8 bl1 = WL[(size_t)(s * 8 + 2 * w + 1) * 64 + lane];
        #pragma unroll
        for (int m = 0; m < 4; ++m) {
            acc[m][0] = __builtin_amdgcn_mfma_f32_16x16x32_bf16(ah[m], bh[s][0], acc[m][0], 0, 0, 0);
            acc[m][0] = __builtin_amdgcn_mfma_f32_16x16x32_bf16(al[m], bh[s][0], acc[m][0], 0, 0, 0);
            acc[m][0] = __builtin_amdgcn_mfma_f32_16x16x32_bf16(ah[m], bl0,      acc[m][0], 0, 0, 0);
            acc[m][1] = __builtin_amdgcn_mfma_f32_16x16x32_bf16(ah[m], bh[s][1], acc[m][1], 0, 0, 0);
            acc[m][1] = __builtin_amdgcn_mfma_f32_16x16x32_bf16(al[m], bh[s][1], acc[m][1], 0, 0, 0);
            acc[m][1] = __builtin_amdgcn_mfma_f32_16x16x32_bf16(ah[m], bl1,      acc[m][1], 0, 0, 0);
        }
    }

    // ---- epilogue: leaky relu + row-wise L2 normalize ----
    // C layout: col = lane&15 (+16*tile), row = 4*(lane>>4) + reg (+16*m)
    float psum[4][4];
    #pragma unroll
    for (int m = 0; m < 4; ++m) {
        #pragma unroll
        for (int r = 0; r < 4; ++r) {
            float ss = 0.f;
            #pragma unroll
            for (int j = 0; j < 2; ++j) {
                float v = acc[m][j][r];
                v = (v >= 0.f) ? v : 0.2f * v;
                acc[m][j][r] = v;
                ss += v * v;
            }
            psum[m][r] = ss;
        }
    }
    #pragma unroll
    for (int m = 0; m < 4; ++m)
        #pragma unroll
        for (int r = 0; r < 4; ++r) {
            float ss = psum[m][r];
            #pragma unroll
            for (int o = 1; o < 16; o <<= 1)
                ss += __shfl_xor(ss, o, 16);
            psum[m][r] = ss;
        }

    if ((lane & 15) == 0) {
        #pragma unroll
        for (int m = 0; m < 4; ++m)
            #pragma unroll
            for (int r = 0; r < 4; ++r)
                nspart[w][m * 16 + 4 * (lane >> 4) + r] = psum[m][r];
    }
    __syncthreads();

    if (t < BM) {
        float tot = nspart[0][t] + nspart[1][t] + nspart[2][t] + nspart[3][t];
        ninv[t] = 1.0f / fmaxf(sqrtf(tot), 1e-12f);
    }
    __syncthreads();

    #pragma unroll
    for (int m = 0; m < 4; ++m) {
        #pragma unroll
        for (int r = 0; r < 4; ++r) {
            int rl  = m * 16 + 4 * (lane >> 4) + r;
            int row = row0 + rl;
            if (row < N) {
                float iv = ninv[rl];
                #pragma unroll
                for (int j = 0; j < 2; ++j) {
                    int col = (2 * w + j) * 16 + (lane & 15);
                    Aout[(size_t)row * D + col] = acc[m][j][r] * iv;
                }
            }
        }
    }
}

// ---------------------------------------------------------------------------
// FALLBACK node update (f32 VALU) — used only on the atomic fallback path.
// ---------------------------------------------------------------------------
__global__ __launch_bounds__(256) void node_gemm(
    const float* __restrict__ ego,
    const float* __restrict__ W1,
    const float* __restrict__ W2,
    float*       __restrict__ Aout,
    int N)
{
    __shared__ float P[ROWS][D];
    __shared__ float Q[ROWS][D];

    const int t    = threadIdx.x;
    const int row0 = blockIdx.x * ROWS;

    const float4* A4 = (const float4*)Aout;
    const float4* G4 = (const float4*)ego;
    #pragma unroll
    for (int i = 0; i < 2; ++i) {
        int idx = t + i * 256;
        int r   = idx >> 5;
        int c4  = idx & 31;
        int row = row0 + r;
        if (row < N) {
            float4 a = A4[(size_t)row * D4 + c4];
            float4 g = G4[(size_t)row * D4 + c4];
            float4 p = {a.x + g.x, a.y + g.y, a.z + g.z, a.w + g.w};
            float4 q = {a.x * g.x, a.y * g.y, a.z * g.z, a.w * g.w};
            *(float4*)&P[r][c4 * 4] = p;
            *(float4*)&Q[r][c4 * 4] = q;
        }
    }
    __syncthreads();

    const int c  = t & 127;
    const int rh = (t >> 7) * 8;
    float acc[8] = {0.f, 0.f, 0.f, 0.f, 0.f, 0.f, 0.f, 0.f};

    for (int k = 0; k < D; k += 4) {
        float w1v[4], w2v[4];
        #pragma unroll
        for (int kk = 0; kk < 4; ++kk) {
            w1v[kk] = W1[(k + kk) * D + c];
            w2v[kk] = W2[(k + kk) * D + c];
        }
        #pragma unroll
        for (int r = 0; r < 8; ++r) {
            float4 p = *(const float4*)&P[rh + r][k];
            float4 q = *(const float4*)&Q[rh + r][k];
            float a = acc[r];
            a = fmaf(p.x, w1v[0], a);
            a = fmaf(p.y, w1v[1], a);
            a = fmaf(p.z, w1v[2], a);
            a = fmaf(p.w, w1v[3], a);
            a = fmaf(q.x, w2v[0], a);
            a = fmaf(q.y, w2v[1], a);
            a = fmaf(q.z, w2v[2], a);
            a = fmaf(q.w, w2v[3], a);
            acc[r] = a;
        }
    }

    __syncthreads();
    #pragma unroll
    for (int r = 0; r < 8; ++r) {
        float h = acc[r];
        h = (h >= 0.f) ? h : 0.2f * h;
        P[rh + r][c] = h;
    }
    __syncthreads();

    const int row = t >> 4;
    const int l   = t & 15;
    float h8[8];
    float ssum = 0.f;
    #pragma unroll
    for (int j = 0; j < 8; ++j) {
        float v = P[row][l * 8 + j];
        h8[j] = v;
        ssum += v * v;
    }
    #pragma unroll
    for (int o = 1; o < 16; o <<= 1)
        ssum += __shfl_xor(ssum, o, 16);

    float inv = 1.0f / fmaxf(sqrtf(ssum), 1e-12f);

    int orow = row0 + row;
    if (orow < N) {
        float4* O4 = (float4*)Aout;
        float4 o0 = {h8[0] * inv, h8[1] * inv, h8[2] * inv, h8[3] * inv};
        float4 o1 = {h8[4] * inv, h8[5] * inv, h8[6] * inv, h8[7] * inv};
        O4[(size_t)orow * D4 + l * 2 + 0] = o0;
        O4[(size_t)orow * D4 + l * 2 + 1] = o1;
    }
}

// ---------------------------------------------------------------------------
extern "C" void kernel_launch(void* const* d_in, const int* in_sizes, int n_in,
                              void* d_out, int out_size, void* d_ws, size_t ws_size,
                              hipStream_t stream)
{
    const float* ego  = (const float*)d_in[0];
    const float* norm = (const float*)d_in[1];
    const int*   src  = (const int*)d_in[2];
    const int*   dst  = (const int*)d_in[3];
    const float* W1   = (const float*)d_in[4];
    const float* W2   = (const float*)d_in[5];

    const int N = in_sizes[1];
    const int E = in_sizes[2];

    float* out = (float*)d_out;   // aggregate A, then overwritten with h

    // Workspace layout
    int*   cnt     = (int*)d_ws;              // N ints (reused as cursor)
    int*   off     = cnt + N;                 // N ints
    int*   srcs    = off + N;                 // E ints
    float* coef    = (float*)(srcs + E);      // E floats
    int*   partial = (int*)(coef + E);        // SCAN_NB ints
    short* whi     = (short*)(partial + SCAN_NB);   // 4096*8 bf16
    short* wlo     = whi + 4096 * 8;                // 4096*8 bf16
    size_t need = ((size_t)2 * N + (size_t)2 * E + SCAN_NB) * sizeof(int)
                + (size_t)2 * 4096 * 8 * sizeof(short);

    if (ws_size >= need) {
        // ---- atomic-free sorted path + MFMA node update ----
        hipMemsetAsync(cnt, 0, (size_t)N * sizeof(int), stream);

        prep_w<<<16, 256, 0, stream>>>(W1, W2, whi, wlo);

        int eb = (E + 255) / 256;
        hist_kernel<<<eb, 256, 0, stream>>>(dst, cnt, E);

        scan_reduce  <<<SCAN_NB, SCAN_BS, 0, stream>>>(cnt, partial, N);
        scan_partials<<<1,       SCAN_NB, 0, stream>>>(partial);
        scan_apply   <<<SCAN_NB, SCAN_BS, 0, stream>>>(cnt, partial, off, cnt, N);

        reorder_kernel<<<eb, 256, 0, stream>>>(src, dst, norm, cnt, srcs, coef, E);

        int gb = (N + 7) / 8;
        aggregate_kernel<<<gb, 256, 0, stream>>>(ego, off, cnt, srcs, coef, out, N);

        int nb = (N + BM - 1) / BM;
        node_gemm_mfma<<<nb, 256, 0, stream>>>(ego, whi, wlo, out, N);
    } else {
        // ---- fallback: atomic scatter + f32 node update ----
        hipMemsetAsync(out, 0, (size_t)N * D * sizeof(float), stream);
        long long total = (long long)E * 32;
        int blocks = (int)((total + 255) / 256);
        edge_scatter<<<blocks, 256, 0, stream>>>(ego, norm, src, dst, out, E);

        int blocks2 = (N + ROWS - 1) / ROWS;
        node_gemm<<<blocks2, 256, 0, stream>>>(ego, W1, W2, out, N);
    }
}